// Round 1
// baseline (24.581 us; speedup 1.0000x reference)
//
#include <hip/hip_runtime.h>

// WisePooling: ragged segment-mean over time axis + EPS.
// input: [B, T, D] float32, graph: [B, S, 2] int32 (start, end inclusive)
// output: [B, S, D] float32 = mean(input[b, start:end+1, :]) + EPS_ADD

#define EPS_ADD 0.006f

// One block per (b, s) segment. 256 threads:
//   group g = tid & 63  -> float4 column group (D = 256 = 64 groups)
//   part  p = tid >> 6  -> row partition (4-way)
__global__ __launch_bounds__(256) void wise_pool_kernel(
    const float* __restrict__ x,   // [B, T, D]
    const int* __restrict__ graph, // [B, S, 2]
    float* __restrict__ out,       // [B, S, D]
    int B, int T, int D, int S)
{
    const int bs = blockIdx.x;        // 0 .. B*S-1
    const int b = bs / S;
    const int s = bs - b * S;

    const int start = graph[(b * S + s) * 2 + 0];
    const int end   = graph[(b * S + s) * 2 + 1];
    const int len   = end - start + 1;

    const int tid = threadIdx.x;
    const int g   = tid & 63;   // float4 group within row
    const int p   = tid >> 6;   // row partition 0..3

    const float4* xrow = reinterpret_cast<const float4*>(x + (size_t)b * T * D);
    const int groups = D >> 2;  // 64

    float4 acc = make_float4(0.f, 0.f, 0.f, 0.f);
    for (int t = start + p; t <= end; t += 4) {
        float4 v = xrow[(size_t)t * groups + g];
        acc.x += v.x; acc.y += v.y; acc.z += v.z; acc.w += v.w;
    }

    __shared__ float4 sm[256];
    sm[tid] = acc;
    __syncthreads();

    if (p == 0) {
        float4 a0 = sm[g];
        float4 a1 = sm[g + 64];
        float4 a2 = sm[g + 128];
        float4 a3 = sm[g + 192];
        float inv = 1.0f / (float)len;
        float4 r;
        r.x = (a0.x + a1.x + a2.x + a3.x) * inv + EPS_ADD;
        r.y = (a0.y + a1.y + a2.y + a3.y) * inv + EPS_ADD;
        r.z = (a0.z + a1.z + a2.z + a3.z) * inv + EPS_ADD;
        r.w = (a0.w + a1.w + a2.w + a3.w) * inv + EPS_ADD;
        reinterpret_cast<float4*>(out)[(size_t)bs * groups + g] = r;
    }
}

extern "C" void kernel_launch(void* const* d_in, const int* in_sizes, int n_in,
                              void* d_out, int out_size, void* d_ws, size_t ws_size,
                              hipStream_t stream) {
    const float* x     = (const float*)d_in[0];
    const int*   graph = (const int*)d_in[1];
    float*       out   = (float*)d_out;

    const int B = 16, T = 8192, D = 256, S = 64;
    // Sanity from sizes: in_sizes[0] == B*T*D, in_sizes[1] == B*S*2
    dim3 grid(B * S);
    dim3 block(256);
    wise_pool_kernel<<<grid, block, 0, stream>>>(x, graph, out, B, T, D, S);
}